// Round 2
// baseline (101.652 us; speedup 1.0000x reference)
//
#include <hip/hip_runtime.h>
#include <math.h>

#define NIN 128
#define NOUT 128
#define BB 4              // batch rows per block
#define NTH 256

// Main dot-product loop. Two batch rows per thread; x-row values are
// wave-uniform -> scalar loads (s_load) via readfirstlane'd base pointer.
template <bool STATS>
__device__ __forceinline__ void dot_loop(
    const float4* __restrict__ w4, const float4* __restrict__ b4,
    const float* __restrict__ xr0, const float* __restrict__ xr1,
    float& acb0, float& acw0, float& acb1, float& acw1,
    float& uu, float& bw, float& ww)
{
    #pragma unroll
    for (int kc = 0; kc < NIN / 4; ++kc) {
        const float4 wv = w4[kc];
        const float4 bv = b4[kc];
        if (STATS) {
            uu = fmaf(bv.x, bv.x, uu); uu = fmaf(bv.y, bv.y, uu);
            uu = fmaf(bv.z, bv.z, uu); uu = fmaf(bv.w, bv.w, uu);
            bw = fmaf(bv.x, wv.x, bw); bw = fmaf(bv.y, wv.y, bw);
            bw = fmaf(bv.z, wv.z, bw); bw = fmaf(bv.w, wv.w, bw);
            ww = fmaf(wv.x, wv.x, ww); ww = fmaf(wv.y, wv.y, ww);
            ww = fmaf(wv.z, wv.z, ww); ww = fmaf(wv.w, wv.w, ww);
        }
        const float x00 = xr0[kc * 4 + 0], x01 = xr0[kc * 4 + 1];
        const float x02 = xr0[kc * 4 + 2], x03 = xr0[kc * 4 + 3];
        const float x10 = xr1[kc * 4 + 0], x11 = xr1[kc * 4 + 1];
        const float x12 = xr1[kc * 4 + 2], x13 = xr1[kc * 4 + 3];
        acb0 = fmaf(x00, bv.x, acb0); acb0 = fmaf(x01, bv.y, acb0);
        acb0 = fmaf(x02, bv.z, acb0); acb0 = fmaf(x03, bv.w, acb0);
        acw0 = fmaf(x00, wv.x, acw0); acw0 = fmaf(x01, wv.y, acw0);
        acw0 = fmaf(x02, wv.z, acw0); acw0 = fmaf(x03, wv.w, acw0);
        acb1 = fmaf(x10, bv.x, acb1); acb1 = fmaf(x11, bv.y, acb1);
        acb1 = fmaf(x12, bv.z, acb1); acb1 = fmaf(x13, bv.w, acb1);
        acw1 = fmaf(x10, wv.x, acw1); acw1 = fmaf(x11, wv.y, acw1);
        acw1 = fmaf(x12, wv.z, acw1); acw1 = fmaf(x13, wv.w, acw1);
    }
}

__global__ __launch_bounds__(NTH) void hyper_kernel(
    const float* __restrict__ x,
    const float* __restrict__ weight,
    const float* __restrict__ bias,
    float* __restrict__ out)
{
    __shared__ float svv[BB];
    __shared__ float s_uu[NOUT];
    __shared__ float s_bw[NOUT];
    __shared__ float s_ww[NOUT];

    const int tid = threadIdx.x;
    const int b0 = blockIdx.x * BB;
    const int o = tid & (NOUT - 1);
    const int rh = tid >> 7;                 // 0 or 1 (wave-uniform)

    // ---- vv[r] = ||x[b0+r]||^2 : threads 0..127 (waves 0,1), 32 lanes/row
    if (tid < 32 * BB) {
        const int r = tid >> 5, seg = tid & 31;
        const float4 v = *(const float4*)(x + (size_t)(b0 + r) * NIN + seg * 4);
        float s = fmaf(v.x, v.x, fmaf(v.y, v.y, fmaf(v.z, v.z, v.w * v.w)));
        s += __shfl_xor(s, 1);
        s += __shfl_xor(s, 2);
        s += __shfl_xor(s, 4);
        s += __shfl_xor(s, 8);
        s += __shfl_xor(s, 16);
        if (seg == 0) svv[r] = s;
    }

    const int row0 = b0 + rh * 2;
    // wave-uniform x-row base -> scalar loads
    const float* xr0 = x + (size_t)((unsigned)__builtin_amdgcn_readfirstlane(row0)) * NIN;
    const float* xr1 = xr0 + NIN;
    const float4* w4 = (const float4*)(weight + (size_t)o * NIN);
    const float4* b4 = (const float4*)(bias + (size_t)o * NIN);

    float acb0 = 0.f, acw0 = 0.f, acb1 = 0.f, acw1 = 0.f;
    float uu = 0.f, bw = 0.f, ww = 0.f;

    if (rh == 0) {
        dot_loop<true>(w4, b4, xr0, xr1, acb0, acw0, acb1, acw1, uu, bw, ww);
        s_uu[o] = uu; s_bw[o] = bw; s_ww[o] = ww;
    } else {
        dot_loop<false>(w4, b4, xr0, xr1, acb0, acw0, acb1, acw1, uu, bw, ww);
    }
    __syncthreads();
    uu = s_uu[o]; bw = s_bw[o]; ww = s_ww[o];
    const float vv0 = svv[rh * 2 + 0];
    const float vv1 = svv[rh * 2 + 1];

    // ---- epilogue (fp32, numerically stable softplus)
    const float EPS = 1.1920928955078125e-7f;
    const float CLAMPV = 16.635532333438687f;
    const float INV_SMOOTH = 1.f / 50.f;
    const float SMOOTHF = 50.f;
    const float MAXNORM = 1.f - 1e-5f;

    const float beta = 1.f - uu;
    const float beta_c = fmaxf(beta, EPS);
    const float a_norm = fmaxf(beta_c * sqrtf(ww), 1e-15f);
    const float ba = beta_c * bw;
    const float outcoef = (2.f / beta_c) * a_norm;
    const float inv_anorm = 1.f / a_norm;

    float accb[2] = {acb0, acb1};
    float accw[2] = {acw0, acw1};
    float vvs[2] = {vv0, vv1};

    #pragma unroll
    for (int r = 0; r < 2; ++r) {
        const float vv = vvs[r];
        const float uv = -accb[r];
        const float dax = beta_c * accw[r];
        const float alpha = 1.f + 2.f * uv + vv;
        const float den = fmaxf(1.f + 2.f * uv + uu * vv, EPS);
        const float inv_den = 1.f / den;
        float suba = (beta * dax - alpha * ba) * inv_den;
        float ss = (alpha * alpha * uu + 2.f * alpha * beta * uv + beta * beta * vv)
                   * (inv_den * inv_den);
        const float nrm = fmaxf(sqrtf(fmaxf(ss, 0.f)), 1e-15f);
        if (nrm > MAXNORM) {
            const float sc = MAXNORM / nrm;
            suba *= sc;
            ss *= sc * sc;
        }
        const float lam_sub = 2.f / fmaxf(1.f - ss, EPS);
        const float arg = lam_sub * suba * inv_anorm;
        const float t1 = SMOOTHF * (arg + CLAMPV);
        const float t2 = SMOOTHF * (arg - CLAMPV);
        const float sp1 = fmaxf(t1, 0.f) + log1pf(expf(-fabsf(t1)));
        const float sp2 = fmaxf(t2, 0.f) + log1pf(expf(-fabsf(t2)));
        const float scl = -CLAMPV + (sp1 - sp2) * INV_SMOOTH;
        const float sd = asinhf(scl);
        out[(size_t)(row0 + r) * NOUT + o] = outcoef * sd;
    }
}

extern "C" void kernel_launch(void* const* d_in, const int* in_sizes, int n_in,
                              void* d_out, int out_size, void* d_ws, size_t ws_size,
                              hipStream_t stream) {
    const float* x = (const float*)d_in[0];
    const float* w = (const float*)d_in[1];
    const float* b = (const float*)d_in[2];
    float* out = (float*)d_out;
    const int B = in_sizes[0] / NIN;       // 4096
    dim3 grid(B / BB), block(NTH);
    hipLaunchKernelGGL(hyper_kernel, grid, block, 0, stream, x, w, b, out);
}